// Round 3
// baseline (236.971 us; speedup 1.0000x reference)
//
#include <hip/hip_runtime.h>

typedef float vf4 __attribute__((ext_vector_type(4)));

#define IN_F 1024
#define IN_F4 256   // float4 per x row
#define OUT_F4 256  // float4 per out row
#define SCALING 0.25f
#define ROWS_PER_WAVE 8
#define BLOCK 256

// Load one 2-row group: 8 float4 per lane, fully coalesced (1 KB per instr).
__device__ __forceinline__ void load_pair(const vf4* __restrict__ x4, int row,
                                          int lane, vf4* xb) {
#pragma unroll
  for (int w = 0; w < 4; ++w)
    xb[w] = x4[(size_t)row * IN_F4 + w * 64 + lane];
#pragma unroll
  for (int w = 0; w < 4; ++w)
    xb[4 + w] = x4[(size_t)(row + 1) * IN_F4 + w * 64 + lane];
}

// One row: rank-4 dot partials -> 6-stage butterfly -> expand 16 outputs.
// A/B base pointers are laundered per call so the unrolled straight-line
// rows cannot CSE the A/B loads into 128 hoisted VGPRs (they are L1-hot;
// re-reading keeps VGPR <= ~128 for 16 waves/CU of MLP).
__device__ __forceinline__ void row_dot_expand(const vf4* A4, const vf4* B4,
                                               vf4* __restrict__ out4,
                                               const vf4* xb, int row,
                                               int lane) {
  __asm__("" : "+s"(A4));
  __asm__("" : "+s"(B4));
  float h0 = 0.f, h1 = 0.f, h2 = 0.f, h3 = 0.f;
#pragma unroll
  for (int w = 0; w < 4; ++w) {
    const vf4 xv = xb[w];
    const vf4 a0 = A4[0 * IN_F4 + w * 64 + lane];
    const vf4 a1 = A4[1 * IN_F4 + w * 64 + lane];
    const vf4 a2 = A4[2 * IN_F4 + w * 64 + lane];
    const vf4 a3 = A4[3 * IN_F4 + w * 64 + lane];
    h0 += xv.x * a0.x + xv.y * a0.y + xv.z * a0.z + xv.w * a0.w;
    h1 += xv.x * a1.x + xv.y * a1.y + xv.z * a1.z + xv.w * a1.w;
    h2 += xv.x * a2.x + xv.y * a2.y + xv.z * a2.z + xv.w * a2.w;
    h3 += xv.x * a3.x + xv.y * a3.y + xv.z * a3.z + xv.w * a3.w;
  }
#pragma unroll
  for (int off = 32; off > 0; off >>= 1) {
    h0 += __shfl_xor(h0, off, 64);
    h1 += __shfl_xor(h1, off, 64);
    h2 += __shfl_xor(h2, off, 64);
    h3 += __shfl_xor(h3, off, 64);
  }
  h0 *= SCALING; h1 *= SCALING; h2 *= SCALING; h3 *= SCALING;
#pragma unroll
  for (int w = 0; w < 4; ++w) {
    const int e = 4 * (w * 64 + lane);
    const vf4 b0 = B4[e + 0];
    const vf4 b1 = B4[e + 1];
    const vf4 b2 = B4[e + 2];
    const vf4 b3 = B4[e + 3];
    vf4 res;
    res.x = h0 * b0.x + h1 * b0.y + h2 * b0.z + h3 * b0.w;
    res.y = h0 * b1.x + h1 * b1.y + h2 * b1.z + h3 * b1.w;
    res.z = h0 * b2.x + h1 * b2.y + h2 * b2.z + h3 * b2.w;
    res.w = h0 * b3.x + h1 * b3.y + h2 * b3.z + h3 * b3.w;
    // NT store: keep the 131 MB out-stream out of LLC so x stays resident.
    __builtin_nontemporal_store(res, &out4[(size_t)row * OUT_F4 + w * 64 + lane]);
  }
}

__device__ __forceinline__ void process_pair(const vf4* A4, const vf4* B4,
                                             vf4* __restrict__ out4,
                                             const vf4* xb, int row, int lane) {
  row_dot_expand(A4, B4, out4, xb, row, lane);
  row_dot_expand(A4, B4, out4, xb + 4, row + 1, lane);
}

// Streaming LoRA: 1 wave x 8 rows as 4 pairs, pair-granular double buffer.
// Straight-line pipeline keeps pair p+1 (8 KB/wave) in flight during pair p.
__global__ __launch_bounds__(BLOCK) void lora_stream(
    const float* __restrict__ xf, const float* __restrict__ Af,
    const float* __restrict__ Bf, float* __restrict__ outf, int nrows) {
  const int lane = threadIdx.x & 63;
  const int wave = threadIdx.x >> 6;
  const int wid = blockIdx.x * (BLOCK / 64) + wave;
  const int row0 = wid * ROWS_PER_WAVE;
  if (row0 >= nrows) return;

  const vf4* x4 = (const vf4*)xf;
  const vf4* A4 = (const vf4*)Af;
  const vf4* B4 = (const vf4*)Bf;
  vf4* out4 = (vf4*)outf;

  if (row0 + ROWS_PER_WAVE <= nrows) {
    vf4 bufA[8], bufB[8];
    load_pair(x4, row0 + 0, lane, bufA);
    load_pair(x4, row0 + 2, lane, bufB);
    process_pair(A4, B4, out4, bufA, row0 + 0, lane);
    load_pair(x4, row0 + 4, lane, bufA);
    process_pair(A4, B4, out4, bufB, row0 + 2, lane);
    load_pair(x4, row0 + 6, lane, bufB);
    process_pair(A4, B4, out4, bufA, row0 + 4, lane);
    process_pair(A4, B4, out4, bufB, row0 + 6, lane);
  } else {
    // Tail fallback (not taken for 32768 rows).
    for (int row = row0; row < nrows; ++row) {
      vf4 xb[4];
#pragma unroll
      for (int w = 0; w < 4; ++w)
        xb[w] = x4[(size_t)row * IN_F4 + w * 64 + lane];
      row_dot_expand(A4, B4, out4, xb, row, lane);
    }
  }
}

extern "C" void kernel_launch(void* const* d_in, const int* in_sizes, int n_in,
                              void* d_out, int out_size, void* d_ws,
                              size_t ws_size, hipStream_t stream) {
  const float* x = (const float*)d_in[0];
  const float* A = (const float*)d_in[1];
  const float* B = (const float*)d_in[2];
  float* out = (float*)d_out;

  const int nrows = in_sizes[0] / IN_F;  // 32768
  const int waves = (nrows + ROWS_PER_WAVE - 1) / ROWS_PER_WAVE;
  const int blocks = (waves + (BLOCK / 64) - 1) / (BLOCK / 64);  // 1024
  lora_stream<<<blocks, BLOCK, 0, stream>>>(x, A, B, out, nrows);
}